// Round 1
// baseline (3643.609 us; speedup 1.0000x reference)
//
#include <hip/hip_runtime.h>
#include <cstdint>
#include <cstddef>

// Problem constants
#define B_   64
#define S_   512
#define ISZ  256
#define HSZ  512
#define NG   2048    // 4*H

typedef unsigned short u16;
typedef unsigned int   u32;
typedef unsigned long long u64;
typedef __attribute__((ext_vector_type(8))) short short8;
typedef __attribute__((ext_vector_type(4))) float floatx4;

// Workspace layout (bytes), total ~57.1 MB
static const size_t OFF_WPACK = 0;                        // 2*2048*768*2 = 6,291,456
static const size_t OFF_XB    = 6291456;                  // 512*64*256*2 = 16,777,216
static const size_t OFF_HB    = OFF_XB + 16777216;        // tagged h tiles: 2 parity * 2 dir * 4 bg * 32 c * 256 u32 * 4B = 524,288
static const size_t OFF_STAGE = OFF_HB + 524288;          // 512*64*512*2B = 33,554,432 (bwd h, bf16)

__device__ __forceinline__ u16 f2bf(float f) {
    uint32_t u = __float_as_uint(f);
    return (u16)((u + 0x7fffu + ((u >> 16) & 1u)) >> 16);  // RNE
}
__device__ __forceinline__ float sigmoidf_(float x) {
    return 1.0f / (1.0f + __expf(-x));
}
__device__ __forceinline__ float tanhf_(float x) {
    return 1.0f - 2.0f / (__expf(2.0f * x) + 1.0f);
}

// ---------------------------------------------------------------------------
// Pack W_f / W_b (768 x 2048 f32, row-major) into bf16 MFMA-B-fragment order,
// gate-interleaved per 16-hidden-unit chunk:
//   flat = ((dir*128 + nb)*24 + kb)*512 + lane*8 + j ;  nb = 4c+gate
// ---------------------------------------------------------------------------
__global__ __launch_bounds__(256) void pack_w(const float* __restrict__ Wf,
                                              const float* __restrict__ Wb,
                                              u16* __restrict__ wpack) {
    int tid = blockIdx.x * 256 + threadIdx.x;   // over 768*2048
    int dir = blockIdx.y;
    int p = tid & 2047;
    int k = tid >> 11;
    int gate = (p >> 4) & 3;
    int hid  = (p >> 6) * 16 + (p & 15);
    int col  = gate * HSZ + hid;
    const float* W = dir ? Wb : Wf;
    float v = W[(size_t)k * NG + col];
    int nb   = p >> 4;
    int lane = ((k & 31) >> 3) * 16 + (p & 15);
    size_t idx = (((size_t)(dir * 128 + nb) * 24 + (k >> 5)) * 512) + lane * 8 + (k & 7);
    wpack[idx] = f2bf(v);
}

// inputs (B,S,I) f32 -> Xb [t][b][i] bf16
__global__ __launch_bounds__(256) void pack_x(const float* __restrict__ x,
                                              u16* __restrict__ xb) {
    int tid = blockIdx.x * 256 + threadIdx.x;   // over S*B*I = 8,388,608
    int i = tid & 255;
    int b = (tid >> 8) & 63;
    int t = tid >> 14;
    xb[tid] = f2bf(x[((size_t)b * S_ + t) * ISZ + i]);
}

// ---------------------------------------------------------------------------
// Persistent BiLSTM. grid = 256 blocks x 64 threads (one wave per block).
//   chain = blockIdx&7 (dir = chain>>2, bg = chain&3), c = blockIdx>>3.
//
// TAG-IN-DATA handshake (replaces h-store/drain/flag/poll of the prior rev):
//   h published as u32 = (bf16 h << 16) | (t+1), in a private contiguous
//   1KB tile per (parity, dir, bg, c). Producer: 2 coalesced atomic u64
//   stores per lane (hid-pairs packed via shfl_xor) -- NO vmcnt drain, NO
//   flag. Consumer: prefetch all 64 u64 (32KB coalesced), verify ONE tag
//   per u64 (the 8B store is atomic, so one tag validates both halves);
//   re-prefetch everything until all tags == t. Data arrival IS the sync.
//
// Overwrite safety (same parity double-buffer invariant as before): a block
// writes h(t+1) over the slot holding h(t-1) only after it observed tag t+1
// from EVERY tile, which proves every block finished consuming h(t-1).
// ---------------------------------------------------------------------------
__global__ __launch_bounds__(64, 1) void bilstm_persistent(
    const u16* __restrict__ wpack, const u16* __restrict__ xb,
    u32* __restrict__ hbuf,
    const float* __restrict__ bf_, const float* __restrict__ bb_,
    float* __restrict__ out, u16* __restrict__ stage)
{
    const int l  = threadIdx.x;
    const int lm = l & 15;
    const int lq = l >> 4;
    const int chain = blockIdx.x & 7;
    const int c     = blockIdx.x >> 3;
    const int dir   = chain >> 2;
    const int bg    = chain & 3;

    __shared__ u16 wlds[4 * 16 * 512];   // 65536 B: h-part W, [(g*16+kh)*512 + lane*8 + j]

    // ---- stage h-part W into LDS (once) ----
#pragma unroll
    for (int g = 0; g < 4; ++g)
        for (int kh = 0; kh < 16; ++kh) {
            const u16* src = wpack + ((size_t)(dir * 128 + c * 4 + g) * 24 + 8 + kh) * 512 + l * 8;
            *(short8*)&wlds[(g * 16 + kh) * 512 + l * 8] = *(const short8*)src;
        }
    __syncthreads();

    const int hid = c * 16 + lm;
    const float* bias = dir ? bb_ : bf_;
    const float Bf = bias[hid];
    const float Bi = bias[HSZ + hid];
    const float Bo = bias[2 * HSZ + hid];
    const float Bg = bias[3 * HSZ + hid];
    float cst[4] = {0.f, 0.f, 0.f, 0.f};

    const u16* abx = xb + ((size_t)(bg * 16 + lm)) * ISZ + lq * 8;   // + tx*B_*ISZ
    const u16* wx  = wpack + ((size_t)(dir * 128 + c * 4) * 24) * 512 + l * 8;  // +(g*24+kb)*512

    // consumer: u64 base of the (parity,dir,bg) 32-tile span (tile = 128 u64)
    const u64* hb0 = (const u64*)hbuf + ((size_t)(0 * 2 + dir) * 4 + bg) * 32 * 128;
    const u64* hb1 = (const u64*)hbuf + ((size_t)(1 * 2 + dir) * 4 + bg) * 32 * 128;
    // lane-static u64 offset: tile (lq>>1 of each kb-pair), row lm, half (lq&1)
    const int lane_off = lm * 8 + (lq & 1) * 4 + (lq >> 1) * 128;

    // producer: u32 base of own tile, per parity
    u32* wt0 = hbuf + (((size_t)(0 * 2 + dir) * 4 + bg) * 32 + c) * 256;
    u32* wt1 = hbuf + (((size_t)(1 * 2 + dir) * 4 + bg) * 32 + c) * 256;
    const bool evenlane = (lm & 1) == 0;
    const int offA = evenlane ? (lq * 4 + 0) * 16 + lm : (lq * 4 + 1) * 16 + (lm - 1);
    const int offB = evenlane ? (lq * 4 + 2) * 16 + lm : (lq * 4 + 3) * 16 + (lm - 1);

    for (int t = 0; t < S_; ++t) {
        const int tx = dir ? (S_ - 1 - t) : t;

        floatx4 acc0 = (floatx4){0.f, 0.f, 0.f, 0.f};
        floatx4 acc1 = (floatx4){0.f, 0.f, 0.f, 0.f};
        floatx4 acc2 = (floatx4){0.f, 0.f, 0.f, 0.f};
        floatx4 acc3 = (floatx4){0.f, 0.f, 0.f, 0.f};

        // ---- x-part (recurrence-independent; W streams from L2, latency hidden)
        const u16* ax = abx + (size_t)tx * (B_ * ISZ);
#pragma unroll
        for (int kb = 0; kb < 8; ++kb) {
            short8 a  = *(const short8*)(ax + kb * 32);
            short8 w0 = *(const short8*)(wx + (size_t)(0 * 24 + kb) * 512);
            short8 w1 = *(const short8*)(wx + (size_t)(1 * 24 + kb) * 512);
            short8 w2 = *(const short8*)(wx + (size_t)(2 * 24 + kb) * 512);
            short8 w3 = *(const short8*)(wx + (size_t)(3 * 24 + kb) * 512);
            acc0 = __builtin_amdgcn_mfma_f32_16x16x32_bf16(a, w0, acc0, 0, 0, 0);
            acc1 = __builtin_amdgcn_mfma_f32_16x16x32_bf16(a, w1, acc1, 0, 0, 0);
            acc2 = __builtin_amdgcn_mfma_f32_16x16x32_bf16(a, w2, acc2, 0, 0, 0);
            acc3 = __builtin_amdgcn_mfma_f32_16x16x32_bf16(a, w3, acc3, 0, 0, 0);
        }

        // ---- h-part: tagged tiles, self-validating; W from LDS ----
        if (t > 0) {
            const u64* hb = (t & 1) ? hb1 : hb0;   // parity t&1 holds h(t-1)
            const u32 texp = (u32)t;               // tag of h(t-1)

            u64 hq[16][4];
            // prefetch all 64 u64 (32 KB, coalesced)
#pragma unroll
            for (int kb = 0; kb < 16; ++kb)
#pragma unroll
                for (int q = 0; q < 4; ++q)
                    hq[kb][q] = __hip_atomic_load(hb + kb * 256 + lane_off + q,
                                                  __ATOMIC_RELAXED, __HIP_MEMORY_SCOPE_AGENT);
            // gate: all tags fresh, else re-prefetch everything
            for (;;) {
                int ok = 1;
#pragma unroll
                for (int kb = 0; kb < 16; ++kb)
#pragma unroll
                    for (int q = 0; q < 4; ++q)
                        ok &= (((u32)hq[kb][q] & 0xffffu) == texp) ? 1 : 0;
                if (__ballot(ok != 0) == ~0ull) break;
#pragma unroll
                for (int kb = 0; kb < 16; ++kb)
#pragma unroll
                    for (int q = 0; q < 4; ++q)
                        hq[kb][q] = __hip_atomic_load(hb + kb * 256 + lane_off + q,
                                                      __ATOMIC_RELAXED, __HIP_MEMORY_SCOPE_AGENT);
            }

#pragma unroll
            for (int kb = 0; kb < 16; ++kb) {
                union { u32 u[4]; short8 s8; } ua;
#pragma unroll
                for (int q = 0; q < 4; ++q) {
                    u32 wlo = (u32)hq[kb][q];
                    u32 whi = (u32)(hq[kb][q] >> 32);
                    ua.u[q] = __builtin_amdgcn_perm(whi, wlo, 0x07060302u);  // [hi16(lo), hi16(hi)]
                }
                short8 a  = ua.s8;
                short8 w0 = *(const short8*)&wlds[(0 * 16 + kb) * 512 + l * 8];
                short8 w1 = *(const short8*)&wlds[(1 * 16 + kb) * 512 + l * 8];
                short8 w2 = *(const short8*)&wlds[(2 * 16 + kb) * 512 + l * 8];
                short8 w3 = *(const short8*)&wlds[(3 * 16 + kb) * 512 + l * 8];
                acc0 = __builtin_amdgcn_mfma_f32_16x16x32_bf16(a, w0, acc0, 0, 0, 0);
                acc1 = __builtin_amdgcn_mfma_f32_16x16x32_bf16(a, w1, acc1, 0, 0, 0);
                acc2 = __builtin_amdgcn_mfma_f32_16x16x32_bf16(a, w2, acc2, 0, 0, 0);
                acc3 = __builtin_amdgcn_mfma_f32_16x16x32_bf16(a, w3, acc3, 0, 0, 0);
            }
        }

        // ---- cell update: lane l owns batches bg*16+lq*4+r, hid = c*16+lm ----
        float hv[4];
        u32 pk[4];
#pragma unroll
        for (int r = 0; r < 4; ++r) {
            float fg = acc0[r] + Bf;
            float ig = acc1[r] + Bi;
            float og = acc2[r] + Bo;
            float gg = acc3[r] + Bg;
            float cn = sigmoidf_(fg) * cst[r] + sigmoidf_(ig) * tanhf_(gg);
            float hn = sigmoidf_(og) * tanhf_(cn);
            cst[r] = cn;
            hv[r] = hn;
            pk[r] = ((u32)f2bf(hn) << 16) | (u32)(t + 1);
        }

        // ---- publish: pack hid-pairs, 2 atomic u64 stores per lane, no drain ----
        {
            u32* wt = ((t + 1) & 1) ? wt1 : wt0;
            u32 sx0 = __shfl_xor(pk[0], 1);
            u32 sx1 = __shfl_xor(pk[1], 1);
            u32 sx2 = __shfl_xor(pk[2], 1);
            u32 sx3 = __shfl_xor(pk[3], 1);
            u64 vA = evenlane ? (((u64)sx0 << 32) | pk[0]) : (((u64)pk[1] << 32) | sx1);
            u64 vB = evenlane ? (((u64)sx2 << 32) | pk[2]) : (((u64)pk[3] << 32) | sx3);
            __hip_atomic_store((u64*)(wt + offA), vA, __ATOMIC_RELAXED, __HIP_MEMORY_SCOPE_AGENT);
            __hip_atomic_store((u64*)(wt + offB), vB, __ATOMIC_RELAXED, __HIP_MEMORY_SCOPE_AGENT);
        }

        // ---- deferred output (off critical path; plain stores) ----
#pragma unroll
        for (int r = 0; r < 4; ++r) {
            const int b = bg * 16 + lq * 4 + r;
            const size_t oidx = ((size_t)b * S_ + tx) * HSZ + hid;
            if (dir == 0) out[oidx] = 0.5f * hv[r];
            else          stage[oidx] = f2bf(hv[r]);
        }
    }
}

// out[i] += 0.5 * bf16(stage[i]); 4 elems/thread
__global__ __launch_bounds__(256) void combine(float* __restrict__ out,
                                               const u16* __restrict__ stage) {
    int i = (blockIdx.x * 256 + threadIdx.x) * 4;   // over 16,777,216
    ushort4 s = *(const ushort4*)(stage + i);
    float4 o = *(float4*)(out + i);
    o.x += 0.5f * __uint_as_float((uint32_t)s.x << 16);
    o.y += 0.5f * __uint_as_float((uint32_t)s.y << 16);
    o.z += 0.5f * __uint_as_float((uint32_t)s.z << 16);
    o.w += 0.5f * __uint_as_float((uint32_t)s.w << 16);
    *(float4*)(out + i) = o;
}

extern "C" void kernel_launch(void* const* d_in, const int* in_sizes, int n_in,
                              void* d_out, int out_size, void* d_ws, size_t ws_size,
                              hipStream_t stream) {
    const float* x  = (const float*)d_in[0];
    const float* Wf = (const float*)d_in[1];
    const float* bf = (const float*)d_in[2];
    const float* Wb = (const float*)d_in[3];
    const float* bb = (const float*)d_in[4];
    float* out = (float*)d_out;
    char* ws = (char*)d_ws;

    u16* wpack = (u16*)(ws + OFF_WPACK);
    u16* xb    = (u16*)(ws + OFF_XB);
    u32* hbuf  = (u32*)(ws + OFF_HB);
    u16* stage = (u16*)(ws + OFF_STAGE);

    // zero tagged h tiles (tag 0 != any expected tag t>=1)
    (void)hipMemsetAsync(ws + OFF_HB, 0, 524288, stream);

    pack_w<<<dim3(6144, 2), 256, 0, stream>>>(Wf, Wb, wpack);
    pack_x<<<dim3(32768), 256, 0, stream>>>(x, xb);

    bilstm_persistent<<<dim3(256), dim3(64), 0, stream>>>(
        wpack, xb, hbuf, bf, bb, out, stage);

    combine<<<dim3(16384), 256, 0, stream>>>(out, stage);
}